// Round 5
// baseline (46.699 us; speedup 1.0000x reference)
//
#include <hip/hip_runtime.h>

// Batched orthonormalization via Gram-matrix Cholesky (GS == QR == chol(G)):
//   G = V V^T (8x8, 36 unique dots)  -> ONE batched reduction phase, ONE barrier
//   R = chol(G) (upper), C = R^-1    -> tiny, computed redundantly per lane
//   Q = V^T C  (triangular combine)  -> fused multi-axpy + store
// 3 waves (192 threads) per batch, one float4 of each vector per lane.
// Exactly the MGS projection algebra; G is near-diagonal (random Gaussians,
// D=768 >> S=8) so fp32 error ~1e-5, far under the 3.9e-3 threshold.

#define S 8
#define CHUNKS 192  // float4 chunks per vector (768/4)
#define IDX(i, j) ((i)*S - ((i) * ((i) + 1)) / 2 + (j))  // flat upper-tri, i<=j

typedef float f32x4 __attribute__((ext_vector_type(4)));

__device__ __forceinline__ float wave_reduce_sum(float x) {
#pragma unroll
    for (int off = 32; off >= 1; off >>= 1)
        x += __shfl_xor(x, off, 64);
    return x;
}

__global__ __launch_bounds__(192)
void gs_chol_kernel(const float* __restrict__ in, float* __restrict__ out) {
    const int wave = threadIdx.x >> 6;   // 0..2
    const int lane = threadIdx.x & 63;
    const int b = blockIdx.x;
    const int chunk = wave * 64 + lane;  // 0..191

    __shared__ __align__(16) float red[3][36];  // per-wave Gram partials

    // ---- load: one float4 per vector per lane, fully coalesced ----
    float v[S][4];
    const f32x4* src = reinterpret_cast<const f32x4*>(in) + (size_t)b * (S * CHUNKS);
#pragma unroll
    for (int s = 0; s < S; ++s) {
        f32x4 f = src[s * CHUNKS + chunk];
        v[s][0] = f.x; v[s][1] = f.y; v[s][2] = f.z; v[s][3] = f.w;
    }

    // ---- all 36 Gram partial dots (independent FMA chains) ----
    float d[36];
#pragma unroll
    for (int i = 0; i < S; ++i) {
#pragma unroll
        for (int j = 0; j < S; ++j) {
            if (j >= i) {
                float acc = 0.f;
#pragma unroll
                for (int e = 0; e < 4; ++e) acc += v[i][e] * v[j][e];
                d[IDX(i, j)] = acc;
            }
        }
    }

    // ---- 36 pipelined wave reductions ----
#pragma unroll
    for (int t = 0; t < 36; ++t) d[t] = wave_reduce_sum(d[t]);

    // ---- cross-wave combine: ONE barrier ----
    if (lane == 0) {
#pragma unroll
        for (int t = 0; t < 36; t += 4) {
            f32x4 f;
            f.x = d[t]; f.y = d[t + 1]; f.z = d[t + 2]; f.w = d[t + 3];
            *reinterpret_cast<f32x4*>(&red[wave][t]) = f;
        }
    }
    __syncthreads();

    float G[36];
#pragma unroll
    for (int t = 0; t < 36; t += 4) {
        f32x4 a = *reinterpret_cast<const f32x4*>(&red[0][t]);
        f32x4 bb = *reinterpret_cast<const f32x4*>(&red[1][t]);
        f32x4 c = *reinterpret_cast<const f32x4*>(&red[2][t]);
        G[t]     = a.x + bb.x + c.x;
        G[t + 1] = a.y + bb.y + c.y;
        G[t + 2] = a.z + bb.z + c.z;
        G[t + 3] = a.w + bb.w + c.w;
    }

    // ---- in-place Cholesky: G upper triangle becomes R (G = R^T R) ----
    float invd[S];
#pragma unroll
    for (int k = 0; k < S; ++k) {
        float s0 = G[IDX(k, k)];
#pragma unroll
        for (int m = 0; m < S; ++m) {
            if (m < k) { const float r = G[IDX(m, k)]; s0 -= r * r; }
        }
        const float inv = __frsqrt_rn(s0);  // 1/sqrt; diag of R^-1
        invd[k] = inv;
        G[IDX(k, k)] = s0 * inv;            // rkk = s0 / sqrt(s0)
#pragma unroll
        for (int j = 0; j < S; ++j) {
            if (j > k) {
                float t = G[IDX(k, j)];
#pragma unroll
                for (int m = 0; m < S; ++m) {
                    if (m < k) t -= G[IDX(m, k)] * G[IDX(m, j)];
                }
                G[IDX(k, j)] = t * inv;
            }
        }
    }

    // ---- C = R^-1 (upper): back-substitution per column ----
    float C[36];
#pragma unroll
    for (int s = 0; s < S; ++s) {
        C[IDX(s, s)] = invd[s];
#pragma unroll
        for (int jj = 1; jj < S; ++jj) {
            const int j = s - jj;
            if (j >= 0) {
                float t = 0.f;
#pragma unroll
                for (int m = 0; m < S; ++m) {
                    if (m > j && m <= s) t += G[IDX(j, m)] * C[IDX(m, s)];
                }
                C[IDX(j, s)] = -t * invd[j];
            }
        }
    }

    // ---- triangular combine q_s = sum_{j<=s} C[j][s] * v_j, store ----
    f32x4* dst = reinterpret_cast<f32x4*>(out) + (size_t)b * (S * CHUNKS);
#pragma unroll
    for (int s = 0; s < S; ++s) {
        float o0 = 0.f, o1 = 0.f, o2 = 0.f, o3 = 0.f;
#pragma unroll
        for (int j = 0; j < S; ++j) {
            if (j <= s) {
                const float c = C[IDX(j, s)];
                o0 += c * v[j][0]; o1 += c * v[j][1];
                o2 += c * v[j][2]; o3 += c * v[j][3];
            }
        }
        f32x4 f;
        f.x = o0; f.y = o1; f.z = o2; f.w = o3;
        __builtin_nontemporal_store(f, &dst[s * CHUNKS + chunk]);
    }
}

extern "C" void kernel_launch(void* const* d_in, const int* in_sizes, int n_in,
                              void* d_out, int out_size, void* d_ws, size_t ws_size,
                              hipStream_t stream) {
    const float* in = (const float*)d_in[0];
    float* out = (float*)d_out;
    const int B = in_sizes[0] / (S * 768);  // 4096
    gs_chol_kernel<<<B, 192, 0, stream>>>(in, out);
}